// Round 7
// baseline (109.376 us; speedup 1.0000x reference)
//
#include <hip/hip_runtime.h>
#include <math.h>

// AnnealingTopKSoftMax: per-row top-8 mask + softmax over 512-wide rows.
// One wave (64 lanes) per row; lane l owns elements [8l, 8l+8).
//
// R7: merge-reduce butterfly selection (no serial extraction rounds).
//  - lane-local descending sort of 8 owned values (Batcher, 19 CE)
//  - 6 merge steps; at each step merge two sorted-8 lists into their top-8:
//      t[i] = max(v[i], w[7-i])  (bitonic top-8 multiset)  + 12-CE re-sort.
//    Exchange plumbing: steps 1,2,4,8 = DPP row_ror (VALU pipe, fuses into
//    v_max_f32_dpp); steps 16,32 = shfl_xor (DS pipe, only 16 insts/row).
//  - final (xor32) step skips the re-sort: M = max-tree(t), T = min-tree(t),
//    S = sum exp(t-M), need = count(t==T) are all order-independent.
//  - output mask: x > T strictly, plus lowest-global-index tie fill
//    (exact jax.lax.top_k tie-break; proven R3/R6).

#define DEPTH 512

typedef float f32x4 __attribute__((ext_vector_type(4)));

#define CE(arr, i, j)                         \
    do {                                      \
        float _hi = fmaxf(arr[i], arr[j]);    \
        float _lo = fminf(arr[i], arr[j]);    \
        arr[i] = _hi;                         \
        arr[j] = _lo;                         \
    } while (0)

// t = max(cur, DPP_CTRL(src)) — GCNDPPCombine fuses mov_dpp+max into max_dpp.
template <int CTRL>
__device__ __forceinline__ float max_dpp(float cur, float src) {
    int sh = __builtin_amdgcn_update_dpp(__float_as_int(src), __float_as_int(src),
                                         CTRL, 0xF, 0xF, false);
    return fmaxf(cur, __int_as_float(sh));
}

// 12-CE bitonic merge, descending (distances 4,2,1) — R3-proven
#define MERGE12(t)                                          \
    do {                                                    \
        CE(t, 0, 4); CE(t, 1, 5); CE(t, 2, 6); CE(t, 3, 7); \
        CE(t, 0, 2); CE(t, 1, 3); CE(t, 4, 6); CE(t, 5, 7); \
        CE(t, 0, 1); CE(t, 2, 3); CE(t, 4, 5); CE(t, 6, 7); \
    } while (0)

// one ROR-based merge step: v = sorted top-8 of (v, ROR_CTRL(v))
#define ROR_STEP(CTRL)                                      \
    do {                                                    \
        float t[8];                                         \
        t[0] = max_dpp<CTRL>(v[0], v[7]);                   \
        t[1] = max_dpp<CTRL>(v[1], v[6]);                   \
        t[2] = max_dpp<CTRL>(v[2], v[5]);                   \
        t[3] = max_dpp<CTRL>(v[3], v[4]);                   \
        t[4] = max_dpp<CTRL>(v[4], v[3]);                   \
        t[5] = max_dpp<CTRL>(v[5], v[2]);                   \
        t[6] = max_dpp<CTRL>(v[6], v[1]);                   \
        t[7] = max_dpp<CTRL>(v[7], v[0]);                   \
        MERGE12(t);                                         \
        v[0]=t[0]; v[1]=t[1]; v[2]=t[2]; v[3]=t[3];         \
        v[4]=t[4]; v[5]=t[5]; v[6]=t[6]; v[7]=t[7];         \
    } while (0)

__global__ __launch_bounds__(256, 8)
void AnnealingTopKSoftMax_kernel(const float* __restrict__ in,
                                 float* __restrict__ out) {
    const int wave = threadIdx.x >> 6;
    const int lane = threadIdx.x & 63;
    const int row  = (blockIdx.x << 2) | wave;

    const size_t base = (size_t)row * DEPTH + (size_t)lane * 8;
    const f32x4* p = reinterpret_cast<const f32x4*>(in + base);
    const f32x4 a = p[0];
    const f32x4 b = p[1];
    const float x[8] = {a[0], a[1], a[2], a[3], b[0], b[1], b[2], b[3]};

    // ---- lane-local descending sort (Batcher, 19 CE) ----
    float v[8] = {x[0], x[1], x[2], x[3], x[4], x[5], x[6], x[7]};
    CE(v, 0, 1); CE(v, 2, 3); CE(v, 4, 5); CE(v, 6, 7);
    CE(v, 0, 2); CE(v, 1, 3); CE(v, 4, 6); CE(v, 5, 7);
    CE(v, 1, 2); CE(v, 5, 6);
    CE(v, 0, 4); CE(v, 1, 5); CE(v, 2, 6); CE(v, 3, 7);
    CE(v, 2, 4); CE(v, 3, 5);
    CE(v, 1, 2); CE(v, 3, 4); CE(v, 5, 6);

    // ---- 4 DPP row_ror merge steps: each 16-lane row fully reduced ----
    ROR_STEP(0x121);   // row_ror:1
    ROR_STEP(0x122);   // row_ror:2
    ROR_STEP(0x124);   // row_ror:4
    ROR_STEP(0x128);   // row_ror:8

    // ---- cross-row: xor16 (with re-sort), then xor32 (final, no re-sort) ----
    {
        float t[8];
#pragma unroll
        for (int i = 0; i < 8; ++i)
            t[i] = fmaxf(v[i], __shfl_xor(v[7 - i], 16, 64));
        MERGE12(t);
#pragma unroll
        for (int i = 0; i < 8; ++i) v[i] = t[i];
    }
    float t[8];
#pragma unroll
    for (int i = 0; i < 8; ++i)
        t[i] = fmaxf(v[i], __shfl_xor(v[7 - i], 32, 64));

    // t = row's top-8 multiset (order lane-dependent, contents uniform)
    const float m01 = fmaxf(t[0], t[1]), m23 = fmaxf(t[2], t[3]);
    const float m45 = fmaxf(t[4], t[5]), m67 = fmaxf(t[6], t[7]);
    const float M = fmaxf(fmaxf(m01, m23), fmaxf(m45, m67));
    const float n01 = fminf(t[0], t[1]), n23 = fminf(t[2], t[3]);
    const float n45 = fminf(t[4], t[5]), n67 = fminf(t[6], t[7]);
    const float T = fminf(fminf(n01, n23), fminf(n45, n67));

    float S = 0.0f;
#pragma unroll
    for (int i = 0; i < 8; ++i) S += __expf(t[i] - M);

    int need = 0;
#pragma unroll
    for (int i = 0; i < 8; ++i) need += (t[i] == T) ? 1 : 0;

    // per-lane masks over original positions
    unsigned selmask = 0u, eqmask = 0u;
#pragma unroll
    for (int j = 0; j < 8; ++j) {
        selmask |= (x[j] > T ? 1u : 0u) << j;
        eqmask  |= (x[j] == T ? 1u : 0u) << j;
    }

    // tie fill: `need` elements == T at lowest global index (wave-uniform n)
    for (int tt = 0; tt < need; ++tt) {
        const unsigned long long ball = __ballot(eqmask != 0u);
        const int L = __ffsll(ball) - 1;
        if (lane == L) {
            const int j = __ffs(eqmask) - 1;
            selmask |= 1u << j;
            eqmask &= eqmask - 1u;
        }
    }

    const float inv = 1.0f / S;
    f32x4 o0, o1;
#pragma unroll
    for (int j = 0; j < 8; ++j) {
        const float ej = __expf(x[j] - M) * inv;
        const float oj = ((selmask >> j) & 1u) ? ej : 0.0f;
        if (j < 4) o0[j] = oj; else o1[j - 4] = oj;
    }

    f32x4* q = reinterpret_cast<f32x4*>(out + base);
    __builtin_nontemporal_store(o0, q);
    __builtin_nontemporal_store(o1, q + 1);
}

extern "C" void kernel_launch(void* const* d_in, const int* in_sizes, int n_in,
                              void* d_out, int out_size, void* d_ws, size_t ws_size,
                              hipStream_t stream) {
    const float* in = (const float*)d_in[0];
    float* out = (float*)d_out;
    const int rows = in_sizes[0] / DEPTH;      // 131072
    const int blocks = rows / 4;               // 4 waves (rows) per block
    AnnealingTopKSoftMax_kernel<<<blocks, 256, 0, stream>>>(in, out);
}

// Round 8
// 91.241 us; speedup vs baseline: 1.1988x; 1.1988x over previous
//
#include <hip/hip_runtime.h>
#include <math.h>

// AnnealingTopKSoftMax: per-row top-8 mask + softmax over 512-wide rows.
// R8 = R6's algorithm (plain loads, NT stores, serial DPP extraction),
// restructured to TWO independent rows per wave: 4 loads issued upfront
// (2x MLP), two independent selection chains interleaved by the scheduler.
//
// Selection per row (R6-proven):
//  - lane-local descending sort of 8 owned values (Batcher, 19 CE)
//  - 8 rounds: wave-wide max via DPP tree (row_shr 1/2/4/8 + row_bcast
//    15/31 + readlane 63) -> ballot -> lowest winning lane shifts its
//    sorted list down one. Exact top-8 multiset extraction.
//  - M = 1st, T = 8th, S = sum exp(sv-M); mask = x > T strictly, plus
//    lowest-global-index tie fill (exact jax.lax.top_k tie-break).

#define DEPTH 512

typedef float f32x4 __attribute__((ext_vector_type(4)));

#define CE(arr, i, j)                         \
    do {                                      \
        float _hi = fmaxf(arr[i], arr[j]);    \
        float _lo = fminf(arr[i], arr[j]);    \
        arr[i] = _hi;                         \
        arr[j] = _lo;                         \
    } while (0)

template <int CTRL>
__device__ __forceinline__ float dpp_max_step(float v) {
    int vi = __float_as_int(v);
    int sh = __builtin_amdgcn_update_dpp(vi, vi, CTRL, 0xF, 0xF, false);
    return fmaxf(v, __int_as_float(sh));
}

// wave-wide max of 64 lanes, returned as wave-uniform scalar
__device__ __forceinline__ float wave_max64(float v) {
    v = dpp_max_step<0x111>(v);  // row_shr:1
    v = dpp_max_step<0x112>(v);  // row_shr:2
    v = dpp_max_step<0x114>(v);  // row_shr:4
    v = dpp_max_step<0x118>(v);  // row_shr:8
    v = dpp_max_step<0x142>(v);  // row_bcast:15
    v = dpp_max_step<0x143>(v);  // row_bcast:31 -> lane63 = full max
    return __int_as_float(__builtin_amdgcn_readlane(__float_as_int(v), 63));
}

// full per-row pipeline: x[8] (lane-major ownership) -> masked softmax o0,o1
__device__ __forceinline__ void process_row(const float x[8], int lane,
                                            f32x4& o0, f32x4& o1) {
    // lane-local descending sort (Batcher, 19 CE)
    float v[8] = {x[0], x[1], x[2], x[3], x[4], x[5], x[6], x[7]};
    CE(v, 0, 1); CE(v, 2, 3); CE(v, 4, 5); CE(v, 6, 7);
    CE(v, 0, 2); CE(v, 1, 3); CE(v, 4, 6); CE(v, 5, 7);
    CE(v, 1, 2); CE(v, 5, 6);
    CE(v, 0, 4); CE(v, 1, 5); CE(v, 2, 6); CE(v, 3, 7);
    CE(v, 2, 4); CE(v, 3, 5);
    CE(v, 1, 2); CE(v, 3, 4); CE(v, 5, 6);

    // 8 extraction rounds
    float sv[8];
    float M = 0.0f, S = 1.0f;
#pragma unroll
    for (int r = 0; r < 8; ++r) {
        const float m = wave_max64(v[0]);
        sv[r] = m;
        if (r == 0) M = m;
        else        S += __expf(m - M);

        if (r < 7) {
            const unsigned long long ball = __ballot(v[0] == m);
            const int L = __ffsll(ball) - 1;
            const bool win = (lane == L);
            v[0] = win ? v[1] : v[0];
            v[1] = win ? v[2] : v[1];
            v[2] = win ? v[3] : v[2];
            v[3] = win ? v[4] : v[3];
            v[4] = win ? v[5] : v[4];
            v[5] = win ? v[6] : v[5];
            v[6] = win ? v[7] : v[6];
            v[7] = win ? -INFINITY : v[7];
        }
    }

    const float T = sv[7];

    int need = 1;
#pragma unroll
    for (int r = 0; r < 7; ++r) need += (sv[r] == T) ? 1 : 0;

    unsigned selmask = 0u, eqmask = 0u;
#pragma unroll
    for (int j = 0; j < 8; ++j) {
        selmask |= (x[j] > T ? 1u : 0u) << j;
        eqmask  |= (x[j] == T ? 1u : 0u) << j;
    }

    for (int t = 0; t < need; ++t) {
        const unsigned long long ball = __ballot(eqmask != 0u);
        const int L = __ffsll(ball) - 1;
        if (lane == L) {
            const int j = __ffs(eqmask) - 1;
            selmask |= 1u << j;
            eqmask &= eqmask - 1u;
        }
    }

    const float inv = 1.0f / S;
#pragma unroll
    for (int j = 0; j < 8; ++j) {
        const float ej = __expf(x[j] - M) * inv;
        const float oj = ((selmask >> j) & 1u) ? ej : 0.0f;
        if (j < 4) o0[j] = oj; else o1[j - 4] = oj;
    }
}

__global__ __launch_bounds__(256, 8)
void AnnealingTopKSoftMax_kernel(const float* __restrict__ in,
                                 float* __restrict__ out) {
    const int wave = threadIdx.x >> 6;
    const int lane = threadIdx.x & 63;
    const int pair = (blockIdx.x << 2) | wave;     // wave handles rows 2p, 2p+1

    const size_t baseA = (size_t)pair * (2 * DEPTH) + (size_t)lane * 8;
    const size_t baseB = baseA + DEPTH;

    // issue all 4 loads upfront (2x MLP vs one-row-per-wave)
    const f32x4* pA = reinterpret_cast<const f32x4*>(in + baseA);
    const f32x4* pB = reinterpret_cast<const f32x4*>(in + baseB);
    const f32x4 a0 = pA[0];
    const f32x4 a1 = pA[1];
    const f32x4 b0 = pB[0];
    const f32x4 b1 = pB[1];

    const float xA[8] = {a0[0], a0[1], a0[2], a0[3], a1[0], a1[1], a1[2], a1[3]};
    const float xB[8] = {b0[0], b0[1], b0[2], b0[3], b1[0], b1[1], b1[2], b1[3]};

    // two independent chains; scheduler interleaves them
    f32x4 oA0, oA1, oB0, oB1;
    process_row(xA, lane, oA0, oA1);
    process_row(xB, lane, oB0, oB1);

    f32x4* qA = reinterpret_cast<f32x4*>(out + baseA);
    f32x4* qB = reinterpret_cast<f32x4*>(out + baseB);
    __builtin_nontemporal_store(oA0, qA);
    __builtin_nontemporal_store(oA1, qA + 1);
    __builtin_nontemporal_store(oB0, qB);
    __builtin_nontemporal_store(oB1, qB + 1);
}

extern "C" void kernel_launch(void* const* d_in, const int* in_sizes, int n_in,
                              void* d_out, int out_size, void* d_ws, size_t ws_size,
                              hipStream_t stream) {
    const float* in = (const float*)d_in[0];
    float* out = (float*)d_out;
    const int rows = in_sizes[0] / DEPTH;      // 131072
    const int blocks = rows / 8;               // 4 waves/block x 2 rows/wave
    AnnealingTopKSoftMax_kernel<<<blocks, 256, 0, stream>>>(in, out);
}

// Round 9
// 79.184 us; speedup vs baseline: 1.3813x; 1.1523x over previous
//
#include <hip/hip_runtime.h>
#include <math.h>

// AnnealingTopKSoftMax: per-row top-8 mask + softmax over 512-wide rows.
// One wave (64 lanes) per row; lane l owns elements [8l, 8l+8).
//
// R9: op-count diet on R6.
//  - lane-local descending sort (Batcher, 19 CE), as R6.
//  - 8 extraction rounds with POP-ALL-EQUAL: every lane whose head == round
//    max pops (no lowest-lane winner logic). Multiplicity bookkeeping
//    (copies per round, cumulative count, clamp to 8, threshold latch) is
//    SALU-side via ballot popcounts. Exact top-8 multiset => exact M, T, S.
//  - selection mask = (x >= T) used DIRECTLY as v_cmp sgpr-pair masks in
//    cndmask (no per-lane bit assembly). Exact match to jax.lax.top_k
//    whenever count(x>=T)==8; rare duplicate-at-boundary fixed by zeroing
//    the (cnt-8) HIGHEST-index copies of T (top_k keeps lowest indices).

#define DEPTH 512

typedef float f32x4 __attribute__((ext_vector_type(4)));
typedef unsigned long long u64;

#define CE(arr, i, j)                         \
    do {                                      \
        float _hi = fmaxf(arr[i], arr[j]);    \
        float _lo = fminf(arr[i], arr[j]);    \
        arr[i] = _hi;                         \
        arr[j] = _lo;                         \
    } while (0)

template <int CTRL>
__device__ __forceinline__ float dpp_max_step(float v) {
    int vi = __float_as_int(v);
    int sh = __builtin_amdgcn_update_dpp(vi, vi, CTRL, 0xF, 0xF, false);
    return fmaxf(v, __int_as_float(sh));
}

// wave-wide max of 64 lanes, returned as wave-uniform scalar
__device__ __forceinline__ float wave_max64(float v) {
    v = dpp_max_step<0x111>(v);  // row_shr:1
    v = dpp_max_step<0x112>(v);  // row_shr:2
    v = dpp_max_step<0x114>(v);  // row_shr:4
    v = dpp_max_step<0x118>(v);  // row_shr:8
    v = dpp_max_step<0x142>(v);  // row_bcast:15
    v = dpp_max_step<0x143>(v);  // row_bcast:31 -> lane63 = full max
    return __int_as_float(__builtin_amdgcn_readlane(__float_as_int(v), 63));
}

__global__ __launch_bounds__(256, 8)
void AnnealingTopKSoftMax_kernel(const float* __restrict__ in,
                                 float* __restrict__ out) {
    const int wave = threadIdx.x >> 6;
    const int lane = threadIdx.x & 63;
    const int row  = (blockIdx.x << 2) | wave;

    const size_t base = (size_t)row * DEPTH + (size_t)lane * 8;
    const f32x4* p = reinterpret_cast<const f32x4*>(in + base);
    const f32x4 a = p[0];
    const f32x4 b = p[1];
    const float x[8] = {a[0], a[1], a[2], a[3], b[0], b[1], b[2], b[3]};

    // ---- lane-local descending sort (Batcher, 19 CE) ----
    float v[8] = {x[0], x[1], x[2], x[3], x[4], x[5], x[6], x[7]};
    CE(v, 0, 1); CE(v, 2, 3); CE(v, 4, 5); CE(v, 6, 7);
    CE(v, 0, 2); CE(v, 1, 3); CE(v, 4, 6); CE(v, 5, 7);
    CE(v, 1, 2); CE(v, 5, 6);
    CE(v, 0, 4); CE(v, 1, 5); CE(v, 2, 6); CE(v, 3, 7);
    CE(v, 2, 4); CE(v, 3, 5);
    CE(v, 1, 2); CE(v, 3, 4); CE(v, 5, 6);

    // ---- 8 pop-all-equal extraction rounds ----
    float M = 0.0f;          // row max (uniform)
    float S = 0.0f;          // softmax denominator over exact top-8 multiset
    float T = 0.0f;          // 8th largest (latched at cum crossing 8)
    int cum = 0;             // copies popped so far (uniform, SALU)

#pragma unroll
    for (int r = 0; r < 8; ++r) {
        const float m = wave_max64(v[0]);
        const bool eq = (v[0] == m);
        const int c = __popcll(__ballot(eq));   // copies this round (uniform)

        if (r == 0) M = m;

        int kk = 8 - cum;                       // SALU clamp: take at most
        kk = (kk < 0) ? 0 : kk;                 // what's left of the top-8
        kk = (c < kk) ? c : kk;
        const bool crossed = (cum < 8) && (cum + c >= 8);
        T = crossed ? m : T;                    // latch threshold
        cum += c;

        S = fmaf((float)kk, __expf(m - M), S);

        if (r < 7) {                            // pop: every eq-lane shifts
            v[0] = eq ? v[1] : v[0];
            v[1] = eq ? v[2] : v[1];
            v[2] = eq ? v[3] : v[2];
            v[3] = eq ? v[4] : v[3];
            v[4] = eq ? v[5] : v[4];
            v[5] = eq ? v[6] : v[5];
            v[6] = eq ? v[7] : v[6];
            v[7] = eq ? -INFINITY : v[7];
        }
    }

    // ---- output: mask = (x >= T) used directly as cndmask operand ----
    const float inv = __builtin_amdgcn_rcpf(S);
    float o[8];
#pragma unroll
    for (int j = 0; j < 8; ++j) {
        const float e = __expf(x[j] - M) * inv;
        o[j] = (x[j] >= T) ? e : 0.0f;
    }

    // selected-count (uniform); ==8 in all non-degenerate rows
    int cnt = 0;
#pragma unroll
    for (int j = 0; j < 8; ++j) cnt += __popcll(__ballot(x[j] >= T));

    if (cnt > 8) {   // rare exact fixup: zero highest-index copies of T
        int extra = cnt - 8;
        unsigned eqm = 0u;
#pragma unroll
        for (int j = 0; j < 8; ++j) eqm |= (x[j] == T ? 1u : 0u) << j;
        for (int e = 0; e < extra; ++e) {
            const u64 ball = __ballot(eqm != 0u);
            const int L = 63 - __builtin_clzll(ball);   // highest lane
            if (lane == L) {
                const int j = 31 - __builtin_clz(eqm);  // highest slot
                o[j] = 0.0f;
                eqm &= ~(1u << j);
            }
        }
    }

    f32x4 o0, o1;
#pragma unroll
    for (int j = 0; j < 4; ++j) { o0[j] = o[j]; o1[j] = o[j + 4]; }

    f32x4* q = reinterpret_cast<f32x4*>(out + base);
    __builtin_nontemporal_store(o0, q);
    __builtin_nontemporal_store(o1, q + 1);
}

extern "C" void kernel_launch(void* const* d_in, const int* in_sizes, int n_in,
                              void* d_out, int out_size, void* d_ws, size_t ws_size,
                              hipStream_t stream) {
    const float* in = (const float*)d_in[0];
    float* out = (float*)d_out;
    const int rows = in_sizes[0] / DEPTH;      // 131072
    const int blocks = rows / 4;               // 4 waves (rows) per block
    AnnealingTopKSoftMax_kernel<<<blocks, 256, 0, stream>>>(in, out);
}

// Round 10
// 78.465 us; speedup vs baseline: 1.3940x; 1.0092x over previous
//
#include <hip/hip_runtime.h>
#include <math.h>

// AnnealingTopKSoftMax: per-row top-8 mask + softmax over 512-wide rows.
// One wave (64 lanes) per row; lane l owns elements [8l, 8l+8).
//
// R10 = R9 with a VALU diet (algorithm identical, R9-verified):
//  - TRIANGULAR pop-shift: in round r only slots 0..6-r can still reach the
//    head (element at post-shift slot j is read in round r+1+j <= 7), so the
//    shift needs 7-r cndmasks instead of 8 (28 total vs 56). Unread slots
//    keep stale values; -INF fill removed (dead).
//  - round 0: exp(m-M)=1, so S = (float)kk directly (no exp/fma).
//  - selection mask x>=T used directly by cndmask; tie-fixup (rare) zeroes
//    highest-index copies of T. Exact jax.lax.top_k semantics (R9-proven).

#define DEPTH 512

typedef float f32x4 __attribute__((ext_vector_type(4)));
typedef unsigned long long u64;

#define CE(arr, i, j)                         \
    do {                                      \
        float _hi = fmaxf(arr[i], arr[j]);    \
        float _lo = fminf(arr[i], arr[j]);    \
        arr[i] = _hi;                         \
        arr[j] = _lo;                         \
    } while (0)

template <int CTRL>
__device__ __forceinline__ float dpp_max_step(float v) {
    int vi = __float_as_int(v);
    int sh = __builtin_amdgcn_update_dpp(vi, vi, CTRL, 0xF, 0xF, false);
    return fmaxf(v, __int_as_float(sh));
}

// wave-wide max of 64 lanes, returned as wave-uniform scalar
__device__ __forceinline__ float wave_max64(float v) {
    v = dpp_max_step<0x111>(v);  // row_shr:1
    v = dpp_max_step<0x112>(v);  // row_shr:2
    v = dpp_max_step<0x114>(v);  // row_shr:4
    v = dpp_max_step<0x118>(v);  // row_shr:8
    v = dpp_max_step<0x142>(v);  // row_bcast:15
    v = dpp_max_step<0x143>(v);  // row_bcast:31 -> lane63 = full max
    return __int_as_float(__builtin_amdgcn_readlane(__float_as_int(v), 63));
}

__global__ __launch_bounds__(256, 8)
void AnnealingTopKSoftMax_kernel(const float* __restrict__ in,
                                 float* __restrict__ out) {
    const int wave = threadIdx.x >> 6;
    const int lane = threadIdx.x & 63;
    const int row  = (blockIdx.x << 2) | wave;

    const size_t base = (size_t)row * DEPTH + (size_t)lane * 8;
    const f32x4* p = reinterpret_cast<const f32x4*>(in + base);
    const f32x4 a = p[0];
    const f32x4 b = p[1];
    const float x[8] = {a[0], a[1], a[2], a[3], b[0], b[1], b[2], b[3]};

    // ---- lane-local descending sort (Batcher, 19 CE) ----
    float v[8] = {x[0], x[1], x[2], x[3], x[4], x[5], x[6], x[7]};
    CE(v, 0, 1); CE(v, 2, 3); CE(v, 4, 5); CE(v, 6, 7);
    CE(v, 0, 2); CE(v, 1, 3); CE(v, 4, 6); CE(v, 5, 7);
    CE(v, 1, 2); CE(v, 5, 6);
    CE(v, 0, 4); CE(v, 1, 5); CE(v, 2, 6); CE(v, 3, 7);
    CE(v, 2, 4); CE(v, 3, 5);
    CE(v, 1, 2); CE(v, 3, 4); CE(v, 5, 6);

    // ---- 8 pop-all-equal extraction rounds (triangular shift) ----
    float M = 0.0f;          // row max (uniform)
    float S = 0.0f;          // softmax denominator over exact top-8 multiset
    float T = 0.0f;          // 8th largest (latched at cum crossing 8)
    int cum = 0;             // copies popped so far (uniform, SALU)

#pragma unroll
    for (int r = 0; r < 8; ++r) {
        const float m = wave_max64(v[0]);
        const bool eq = (v[0] == m);
        const int c = __popcll(__ballot(eq));   // copies popped this round

        int kk = 8 - cum;                       // clamp to remaining top-8
        kk = (kk < 0) ? 0 : kk;
        kk = (c < kk) ? c : kk;
        const bool crossed = (cum < 8) && (cum + c >= 8);
        T = crossed ? m : T;                    // latch threshold
        cum += c;

        if (r == 0) { M = m; S = (float)kk; }   // exp(0)=1
        else        { S = fmaf((float)kk, __expf(m - M), S); }

        if (r < 7) {                            // triangular shift: 7-r slots
#pragma unroll
            for (int k = 0; k < 7; ++k)
                if (k <= 6 - r) v[k] = eq ? v[k + 1] : v[k];
        }
    }

    // ---- output: mask = (x >= T) used directly as cndmask operand ----
    const float inv = __builtin_amdgcn_rcpf(S);
    float o[8];
#pragma unroll
    for (int j = 0; j < 8; ++j) {
        const float e = __expf(x[j] - M) * inv;
        o[j] = (x[j] >= T) ? e : 0.0f;
    }

    // selected-count (uniform); ==8 in all non-degenerate rows
    int cnt = 0;
#pragma unroll
    for (int j = 0; j < 8; ++j) cnt += __popcll(__ballot(x[j] >= T));

    if (cnt > 8) {   // rare exact fixup: zero highest-index copies of T
        int extra = cnt - 8;
        unsigned eqm = 0u;
#pragma unroll
        for (int j = 0; j < 8; ++j) eqm |= (x[j] == T ? 1u : 0u) << j;
        for (int e = 0; e < extra; ++e) {
            const u64 ball = __ballot(eqm != 0u);
            const int L = 63 - __builtin_clzll(ball);   // highest lane
            if (lane == L) {
                const int j = 31 - __builtin_clz(eqm);  // highest slot
                o[j] = 0.0f;
                eqm &= ~(1u << j);
            }
        }
    }

    f32x4 o0, o1;
#pragma unroll
    for (int j = 0; j < 4; ++j) { o0[j] = o[j]; o1[j] = o[j + 4]; }

    f32x4* q = reinterpret_cast<f32x4*>(out + base);
    __builtin_nontemporal_store(o0, q);
    __builtin_nontemporal_store(o1, q + 1);
}

extern "C" void kernel_launch(void* const* d_in, const int* in_sizes, int n_in,
                              void* d_out, int out_size, void* d_ws, size_t ws_size,
                              hipStream_t stream) {
    const float* in = (const float*)d_in[0];
    float* out = (float*)d_out;
    const int rows = in_sizes[0] / DEPTH;      // 131072
    const int blocks = rows / 4;               // 4 waves (rows) per block
    AnnealingTopKSoftMax_kernel<<<blocks, 256, 0, stream>>>(in, out);
}